// Round 9
// baseline (159.550 us; speedup 1.0000x reference)
//
#include <hip/hip_runtime.h>
#include <hip/hip_bf16.h>
#include <math.h>

// GCN 2-hop + linear(64->2) + log_softmax, N=100000, E=1600000, D=64.
//
// Structure (R8 -> R9): same small-bucket pull algorithm, rebalanced for
// latency hiding:
//  K1 role-split: blocks [0,128) two-pass partition (avg chunk = 32 edges =
//     128B = full line), blocks [128,910) projection u = x @ W^T -> co-
//     scheduled so proj's streaming read fills CUs idle during part ranking.
//  K2 deg: per-bucket LDS histogram -> uq.z = rsqrt(deg+1). 1024 thr.
//  K3 hop1: z = d^2*(d*u + sum dinv_src*u_src)   [z = dinv * true-hop1]
//  K4 hop2: logit = d*(z + sum z_src)+b; log_softmax. 1024 thr, int4 edges.
//
// Invariant: storing z = dinv*x1 makes hop2 need NO source dinv.

#define NODES 100000
#define EDGES 1600000
#define DIM 64

#define PBITS 8
#define PSIZE 256
#define P_BUCKETS 391  // ceil(100000/256)
#define CAP 8192       // edges per bucket (mean 4092, ~64 sigma headroom)

#define PART_BLOCKS 128
#define PART_PAIRS (EDGES / 2 / PART_BLOCKS)  // 6250 pairs per block

#define PROJ_BLOCKS 782
#define NODES_PER_PROJ 128  // 782*128 = 100096 >= NODES
#define K1_BLOCKS (PART_BLOCKS + PROJ_BLOCKS)

// ---------------------------------------------------------------------------
// K1: role-split partition + projection.
__global__ __launch_bounds__(256) void partproj_kernel(
    const void* __restrict__ ei, int* __restrict__ cursor,
    int* __restrict__ ecbuf, const float* __restrict__ x,
    const float* __restrict__ W, float4* __restrict__ uq) {
  const int t = threadIdx.x;
  if (blockIdx.x < PART_BLOCKS) {
    // ---------------- partition role ----------------
    __shared__ int shMode;
    __shared__ int lcnt[P_BUCKETS];
    __shared__ int lbase[P_BUCKETS];
    if (t < 64) {
      const int* p = (const int*)ei;
      unsigned long long ball = __ballot(p[2 * t + 1] == 0);
      if (t == 0) shMode = (ball == ~0ULL) ? 1 : 0;
    }
    for (int i = t; i < P_BUCKETS; i += 256) lcnt[i] = 0;
    __syncthreads();
    const int m = shMode;
    const int pbase = blockIdx.x * PART_PAIRS;

    // pass 1: count targets
    if (m) {
      const longlong2* cp =
          (const longlong2*)((const long long*)ei + EDGES) + pbase;
      for (int i = t; i < PART_PAIRS; i += 256) {
        longlong2 v = cp[i];
        atomicAdd(&lcnt[((int)v.x) >> PBITS], 1);
        atomicAdd(&lcnt[((int)v.y) >> PBITS], 1);
      }
    } else {
      const int2* cp = (const int2*)((const int*)ei + EDGES) + pbase;
      for (int i = t; i < PART_PAIRS; i += 256) {
        int2 v = cp[i];
        atomicAdd(&lcnt[v.x >> PBITS], 1);
        atomicAdd(&lcnt[v.y >> PBITS], 1);
      }
    }
    __syncthreads();
    for (int i = t; i < P_BUCKETS; i += 256) {
      int c = lcnt[i];
      lbase[i] = c ? atomicAdd(&cursor[i], c) : 0;
      lcnt[i] = 0;  // reuse as local rank cursor
    }
    __syncthreads();

    // pass 2: write packed edges (src<<8 | local_col) into reserved chunks
    if (m) {
      const longlong2* rp = (const longlong2*)ei + pbase;
      const longlong2* cp =
          (const longlong2*)((const long long*)ei + EDGES) + pbase;
      for (int i = t; i < PART_PAIRS; i += 256) {
        longlong2 rv = rp[i];
        longlong2 cv = cp[i];
        {
          int r = (int)rv.x, c = (int)cv.x, bk = c >> PBITS;
          int rel = lbase[bk] + atomicAdd(&lcnt[bk], 1);
          if (rel < CAP)
            ecbuf[bk * CAP + rel] = (r << PBITS) | (c & (PSIZE - 1));
        }
        {
          int r = (int)rv.y, c = (int)cv.y, bk = c >> PBITS;
          int rel = lbase[bk] + atomicAdd(&lcnt[bk], 1);
          if (rel < CAP)
            ecbuf[bk * CAP + rel] = (r << PBITS) | (c & (PSIZE - 1));
        }
      }
    } else {
      const int2* rp = (const int2*)ei + pbase;
      const int2* cp = (const int2*)((const int*)ei + EDGES) + pbase;
      for (int i = t; i < PART_PAIRS; i += 256) {
        int2 rv = rp[i];
        int2 cv = cp[i];
        {
          int bk = cv.x >> PBITS;
          int rel = lbase[bk] + atomicAdd(&lcnt[bk], 1);
          if (rel < CAP)
            ecbuf[bk * CAP + rel] = (rv.x << PBITS) | (cv.x & (PSIZE - 1));
        }
        {
          int bk = cv.y >> PBITS;
          int rel = lbase[bk] + atomicAdd(&lcnt[bk], 1);
          if (rel < CAP)
            ecbuf[bk * CAP + rel] = (rv.y << PBITS) | (cv.y & (PSIZE - 1));
        }
      }
    }
  } else {
    // ---------------- projection role: uq.xy = x[i] @ W^T ----------------
    const int nbase = (blockIdx.x - PART_BLOCKS) * NODES_PER_PROJ;
    const int lane16 = t & 15;  // feature quad within node
    const int sub = t >> 4;     // 16 node-slots per pass
    const float4 w0 = *(const float4*)&W[lane16 * 4];
    const float4 w1 = *(const float4*)&W[DIM + lane16 * 4];
    for (int k = sub; k < NODES_PER_PROJ; k += 16) {
      const int node = nbase + k;
      if (node < NODES) {  // uniform within each 16-lane group
        float4 xv = *(const float4*)&x[(size_t)node * DIM + lane16 * 4];
        float p0 = xv.x * w0.x + xv.y * w0.y + xv.z * w0.z + xv.w * w0.w;
        float p1 = xv.x * w1.x + xv.y * w1.y + xv.z * w1.z + xv.w * w1.w;
#pragma unroll
        for (int off = 8; off >= 1; off >>= 1) {
          p0 += __shfl_xor(p0, off, 16);
          p1 += __shfl_xor(p1, off, 16);
        }
        if (lane16 == 0) *(float2*)&uq[node] = make_float2(p0, p1);
      }
    }
  }
}

// ---------------------------------------------------------------------------
// K2: per-bucket degree histogram -> uq.z = rsqrt(deg+1). int4 edge loads.
__global__ __launch_bounds__(1024) void deg_kernel(
    const int* __restrict__ cursor, const int* __restrict__ ecbuf,
    float4* __restrict__ uq) {
  __shared__ int h[PSIZE];
  const int b = blockIdx.x;
  const int t = threadIdx.x;
  if (t < PSIZE) h[t] = 0;
  __syncthreads();
  const int cnt = min(cursor[b], CAP);
  const int4* ep4 = (const int4*)(ecbuf + b * CAP);
  for (int i = t; 4 * i < cnt; i += 1024) {
    int4 v = ep4[i];
    int base = 4 * i;
    if (base + 0 < cnt) atomicAdd(&h[v.x & (PSIZE - 1)], 1);
    if (base + 1 < cnt) atomicAdd(&h[v.y & (PSIZE - 1)], 1);
    if (base + 2 < cnt) atomicAdd(&h[v.z & (PSIZE - 1)], 1);
    if (base + 3 < cnt) atomicAdd(&h[v.w & (PSIZE - 1)], 1);
  }
  __syncthreads();
  if (t < PSIZE) {
    const int node = (b << PBITS) + t;
    if (node < NODES) uq[node].z = rsqrtf((float)(h[t] + 1));
  }
}

// ---------------------------------------------------------------------------
// K3: hop 1. z = d^2*(d*u + sum dinv_src*u_src). 1024 thr, int4 edges.
__global__ __launch_bounds__(1024) void hop1_kernel(
    const int* __restrict__ cursor, const int* __restrict__ ecbuf,
    const float4* __restrict__ uq, float2* __restrict__ z) {
  __shared__ float ax[PSIZE];
  __shared__ float ay[PSIZE];
  const int b = blockIdx.x;
  const int t = threadIdx.x;
  if (t < PSIZE) {
    ax[t] = 0.f;
    ay[t] = 0.f;
  }
  __syncthreads();
  const int cnt = min(cursor[b], CAP);
  const int4* ep4 = (const int4*)(ecbuf + b * CAP);
  for (int i = t; 4 * i < cnt; i += 1024) {
    int4 v = ep4[i];
    int base = 4 * i;
#pragma unroll
    for (int k = 0; k < 4; k++) {
      int pk = (k == 0) ? v.x : (k == 1) ? v.y : (k == 2) ? v.z : v.w;
      if (base + k < cnt) {
        float4 q = uq[pk >> PBITS];
        int l = pk & (PSIZE - 1);
        atomicAdd(&ax[l], q.z * q.x);
        atomicAdd(&ay[l], q.z * q.y);
      }
    }
  }
  __syncthreads();
  if (t < PSIZE) {
    const int node = (b << PBITS) + t;
    if (node < NODES) {
      float4 q = uq[node];
      float d = q.z;
      float s = d * d;
      z[node] = make_float2(s * (ax[t] + d * q.x), s * (ay[t] + d * q.y));
    }
  }
}

// ---------------------------------------------------------------------------
// K4: hop 2 + bias + log_softmax.
__global__ __launch_bounds__(1024) void hop2_kernel(
    const int* __restrict__ cursor, const int* __restrict__ ecbuf,
    const float2* __restrict__ z, const float4* __restrict__ uq,
    const float* __restrict__ bias, float2* __restrict__ out) {
  __shared__ float ax[PSIZE];
  __shared__ float ay[PSIZE];
  const int b = blockIdx.x;
  const int t = threadIdx.x;
  if (t < PSIZE) {
    ax[t] = 0.f;
    ay[t] = 0.f;
  }
  __syncthreads();
  const int cnt = min(cursor[b], CAP);
  const int4* ep4 = (const int4*)(ecbuf + b * CAP);
  for (int i = t; 4 * i < cnt; i += 1024) {
    int4 v = ep4[i];
    int base = 4 * i;
#pragma unroll
    for (int k = 0; k < 4; k++) {
      int pk = (k == 0) ? v.x : (k == 1) ? v.y : (k == 2) ? v.z : v.w;
      if (base + k < cnt) {
        float2 zv = z[pk >> PBITS];
        int l = pk & (PSIZE - 1);
        atomicAdd(&ax[l], zv.x);
        atomicAdd(&ay[l], zv.y);
      }
    }
  }
  __syncthreads();
  if (t < PSIZE) {
    const int node = (b << PBITS) + t;
    if (node < NODES) {
      float d = uq[node].z;
      float2 zi = z[node];
      float l0 = d * (ax[t] + zi.x) + bias[0];
      float l1 = d * (ay[t] + zi.y) + bias[1];
      float m = fmaxf(l0, l1);
      float ls = m + logf(expf(l0 - m) + expf(l1 - m));
      out[node] = make_float2(l0 - ls, l1 - ls);
    }
  }
}

// ---------------------------------------------------------------------------
extern "C" void kernel_launch(void* const* d_in, const int* in_sizes, int n_in,
                              void* d_out, int out_size, void* d_ws,
                              size_t ws_size, hipStream_t stream) {
  const float* x = (const float*)d_in[0];
  const void* ei = d_in[1];
  const float* W = (const float*)d_in[2];
  const float* bias = (const float*)d_in[3];
  float2* out = (float2*)d_out;

  char* w = (char*)d_ws;
  size_t off = 0;
  auto alloc = [&](size_t bytes) -> char* {
    char* p = w + off;
    off += (bytes + 255) & ~(size_t)255;
    return p;
  };
  int* cursor = (int*)alloc(P_BUCKETS * sizeof(int));
  int* ecbuf = (int*)alloc((size_t)P_BUCKETS * CAP * sizeof(int));  // 12.8 MB
  float4* uq = (float4*)alloc((size_t)(P_BUCKETS << PBITS) * sizeof(float4));
  float2* z = (float2*)alloc((size_t)NODES * sizeof(float2));
  (void)ws_size;

  hipMemsetAsync(cursor, 0, P_BUCKETS * sizeof(int), stream);
  partproj_kernel<<<K1_BLOCKS, 256, 0, stream>>>(ei, cursor, ecbuf, x, W, uq);
  deg_kernel<<<P_BUCKETS, 1024, 0, stream>>>(cursor, ecbuf, uq);
  hop1_kernel<<<P_BUCKETS, 1024, 0, stream>>>(cursor, ecbuf, uq, z);
  hop2_kernel<<<P_BUCKETS, 1024, 0, stream>>>(cursor, ecbuf, z, uq, bias, out);
}